// Round 9
// baseline (117.797 us; speedup 1.0000x reference)
//
#include <hip/hip_runtime.h>
#include <math.h>

// 256-point FFT = 16x16 four-step Cooley-Tukey, one batch per 16 lanes,
// TWO batches per thread, software-pipelined: B's 32 loads are issued
// before A's compute so they stay in flight (counted vmcnt) under A's
// entire FFT+twiddle+store -> per-wave MLP duty cycle ~25% -> ~70%.
// Cache policy (round 8 findings): PLAIN loads (input stays ~50% L3
// resident across replays, FETCH 230->131MB) + NT stores (write-once
// output, WRITE_SIZE clean at 267MB). Single wave-private 16x17 LDS
// tile reused A-then-B -> 17.4 KB/block. __launch_bounds__(256,4):
// VGPR cap 128 fits the ~100 live regs; (256,8)/(256,6) force spills.
// No __syncthreads (wave-private LDS, in-order per-wave DS ops).

#define NB 16   // batch-pairs per 256-thread block (32 batches/block)
#define TS 272  // 16*17 floats per-batch tile

__device__ __forceinline__ void wave_fence() {
    __builtin_amdgcn_wave_barrier();
}

__device__ __forceinline__ void fft16(float re[16], float im[16]) {
    // 4-bit bit-reversal permutation (swap i < rev(i))
    {
        float tr, ti;
#define SWP(a, b) tr = re[a]; re[a] = re[b]; re[b] = tr; ti = im[a]; im[a] = im[b]; im[b] = ti;
        SWP(1, 8) SWP(2, 4) SWP(3, 12) SWP(5, 10) SWP(7, 14) SWP(11, 13)
#undef SWP
    }
    const float C[8] = { 1.0f,  0.92387953251f,  0.70710678119f,  0.38268343236f,
                         0.0f, -0.38268343236f, -0.70710678119f, -0.92387953251f };
    const float S16[8] = { 0.0f, -0.38268343236f, -0.70710678119f, -0.92387953251f,
                          -1.0f, -0.92387953251f, -0.70710678119f, -0.38268343236f };
#pragma unroll
    for (int s = 1; s <= 4; ++s) {
        const int len = 1 << s;
        const int half = len >> 1;
        const int step = 16 >> s;
#pragma unroll
        for (int i = 0; i < 16; i += len) {
#pragma unroll
            for (int j = 0; j < half; ++j) {
                const float wr = C[j * step];
                const float wi = S16[j * step];
                const int p = i + j;
                const int q = i + j + half;
                const float vr = re[q] * wr - im[q] * wi;
                const float vi = re[q] * wi + im[q] * wr;
                const float ur = re[p], ui = im[p];
                re[p] = ur + vr; im[p] = ui + vi;
                re[q] = ur - vr; im[q] = ui - vi;
            }
        }
    }
}

// Twiddle + LDS transpose + second FFT + nt store for one batch.
__device__ __forceinline__ void finish_batch(float re[16], float im[16],
                                             float* L, int t,
                                             float* outr, float* outi) {
#pragma unroll
    for (int k = 0; k < 16; ++k) {
        float sv, cv;
        __sincosf(-6.283185307179586f * (float)(t * k) * (1.0f / 256.0f), &sv, &cv);
        const float tr = re[k] * cv - im[k] * sv;
        const float ti = re[k] * sv + im[k] * cv;
        L[17 * t + k] = ti;   // imag rows to LDS; real kept in re[]
        re[k] = tr;
    }
    wave_fence();
#pragma unroll
    for (int n = 0; n < 16; ++n) im[n] = L[17 * n + t];   // imag columns out
    wave_fence();
#pragma unroll
    for (int k = 0; k < 16; ++k) L[17 * t + k] = re[k];   // real rows in
    wave_fence();
#pragma unroll
    for (int n = 0; n < 16; ++n) re[n] = L[17 * n + t];   // real columns out
    wave_fence();

    fft16(re, im);  // X[t + 16*k1] over k1

#pragma unroll
    for (int k = 0; k < 16; ++k) __builtin_nontemporal_store(re[k], outr + t + 16 * k);
#pragma unroll
    for (int k = 0; k < 16; ++k) __builtin_nontemporal_store(im[k], outi + t + 16 * k);
}

__global__ __launch_bounds__(256, 4) void fft256_kernel(const float* __restrict__ x,
                                                        float* __restrict__ out) {
    __shared__ float tile[NB * TS];

    const int tid = threadIdx.x;
    const int sub = tid >> 4;
    const int t   = tid & 15;
    const long b0 = (long)blockIdx.x * (2 * NB) + sub;  // batch A
    const long b1 = b0 + NB;                            // batch B

    const float* xrA = x + b0 * 512;
    const float* xiA = xrA + 256;
    const float* xrB = x + b1 * 512;
    const float* xiB = xrB + 256;

    float reA[16], imA[16], reB[16], imB[16];

    // Issue ALL 64 loads (A then B) before any compute. The compiler's
    // counted vmcnt lets B's 32 ride in flight under A's whole pipeline.
#pragma unroll
    for (int i = 0; i < 16; ++i) reA[i] = xrA[t + 16 * i];
#pragma unroll
    for (int i = 0; i < 16; ++i) imA[i] = xiA[t + 16 * i];
#pragma unroll
    for (int i = 0; i < 16; ++i) reB[i] = xrB[t + 16 * i];
#pragma unroll
    for (int i = 0; i < 16; ++i) imB[i] = xiB[t + 16 * i];

    float* L = tile + sub * TS;  // wave-private 16x17 tile, reused A then B

    // ---- Batch A
    fft16(reA, imA);
    finish_batch(reA, imA, L, t, out + b0 * 512, out + b0 * 512 + 256);

    // ---- Batch B (loads long since landed)
    fft16(reB, imB);
    finish_batch(reB, imB, L, t, out + b1 * 512, out + b1 * 512 + 256);
}

extern "C" void kernel_launch(void* const* d_in, const int* in_sizes, int n_in,
                              void* d_out, int out_size, void* d_ws, size_t ws_size,
                              hipStream_t stream) {
    (void)d_ws; (void)ws_size; (void)n_in; (void)out_size;
    const float* x = (const float*)d_in[0];
    float* out = (float*)d_out;
    const int batches = in_sizes[0] / 512;        // 131072
    const int grid = batches / (2 * NB);          // 4096 blocks
    fft256_kernel<<<grid, 256, 0, stream>>>(x, out);
}

// Round 10
// 116.603 us; speedup vs baseline: 1.0102x; 1.0102x over previous
//
#include <hip/hip_runtime.h>
#include <math.h>

// 256-point FFT = 16x16 four-step Cooley-Tukey, one batch per 16 lanes,
// TWO batches per thread, software-pipelined: B's 32 loads issue before
// A's compute and ride in flight (counted vmcnt) under A's whole
// FFT+twiddle+store pipeline. Round 9 showed the (256,4) launch bound
// still let the backend target the 64-VGPR tier and SPILL the 2-batch
// state (FETCH +36MB, WRITE +70MB scratch traffic). This round's single
// change: amdgpu_waves_per_eu(2,4) -> VGPR budget 256, no spills.
// Cache policy (round 8): PLAIN loads (input ~50% L3-resident across
// replays) + NT stores (write-once output). Single wave-private 16x17
// LDS tile reused A-then-B -> 17.4 KB/block. No __syncthreads.

#define NB 16   // batch-pairs per 256-thread block (32 batches/block)
#define TS 272  // 16*17 floats per-batch tile

__device__ __forceinline__ void wave_fence() {
    __builtin_amdgcn_wave_barrier();
}

__device__ __forceinline__ void fft16(float re[16], float im[16]) {
    // 4-bit bit-reversal permutation (swap i < rev(i))
    {
        float tr, ti;
#define SWP(a, b) tr = re[a]; re[a] = re[b]; re[b] = tr; ti = im[a]; im[a] = im[b]; im[b] = ti;
        SWP(1, 8) SWP(2, 4) SWP(3, 12) SWP(5, 10) SWP(7, 14) SWP(11, 13)
#undef SWP
    }
    const float C[8] = { 1.0f,  0.92387953251f,  0.70710678119f,  0.38268343236f,
                         0.0f, -0.38268343236f, -0.70710678119f, -0.92387953251f };
    const float S16[8] = { 0.0f, -0.38268343236f, -0.70710678119f, -0.92387953251f,
                          -1.0f, -0.92387953251f, -0.70710678119f, -0.38268343236f };
#pragma unroll
    for (int s = 1; s <= 4; ++s) {
        const int len = 1 << s;
        const int half = len >> 1;
        const int step = 16 >> s;
#pragma unroll
        for (int i = 0; i < 16; i += len) {
#pragma unroll
            for (int j = 0; j < half; ++j) {
                const float wr = C[j * step];
                const float wi = S16[j * step];
                const int p = i + j;
                const int q = i + j + half;
                const float vr = re[q] * wr - im[q] * wi;
                const float vi = re[q] * wi + im[q] * wr;
                const float ur = re[p], ui = im[p];
                re[p] = ur + vr; im[p] = ui + vi;
                re[q] = ur - vr; im[q] = ui - vi;
            }
        }
    }
}

// Twiddle + LDS transpose + second FFT + nt store for one batch.
__device__ __forceinline__ void finish_batch(float re[16], float im[16],
                                             float* L, int t,
                                             float* outr, float* outi) {
#pragma unroll
    for (int k = 0; k < 16; ++k) {
        float sv, cv;
        __sincosf(-6.283185307179586f * (float)(t * k) * (1.0f / 256.0f), &sv, &cv);
        const float tr = re[k] * cv - im[k] * sv;
        const float ti = re[k] * sv + im[k] * cv;
        L[17 * t + k] = ti;   // imag rows to LDS; real kept in re[]
        re[k] = tr;
    }
    wave_fence();
#pragma unroll
    for (int n = 0; n < 16; ++n) im[n] = L[17 * n + t];   // imag columns out
    wave_fence();
#pragma unroll
    for (int k = 0; k < 16; ++k) L[17 * t + k] = re[k];   // real rows in
    wave_fence();
#pragma unroll
    for (int n = 0; n < 16; ++n) re[n] = L[17 * n + t];   // real columns out
    wave_fence();

    fft16(re, im);  // X[t + 16*k1] over k1

#pragma unroll
    for (int k = 0; k < 16; ++k) __builtin_nontemporal_store(re[k], outr + t + 16 * k);
#pragma unroll
    for (int k = 0; k < 16; ++k) __builtin_nontemporal_store(im[k], outi + t + 16 * k);
}

__global__ void __attribute__((amdgpu_waves_per_eu(2, 4)))
fft256_kernel(const float* __restrict__ x, float* __restrict__ out) {
    __shared__ float tile[NB * TS];

    const int tid = threadIdx.x;
    const int sub = tid >> 4;
    const int t   = tid & 15;
    const long b0 = (long)blockIdx.x * (2 * NB) + sub;  // batch A
    const long b1 = b0 + NB;                            // batch B

    const float* xrA = x + b0 * 512;
    const float* xiA = xrA + 256;
    const float* xrB = x + b1 * 512;
    const float* xiB = xrB + 256;

    float reA[16], imA[16], reB[16], imB[16];

    // Issue ALL 64 loads (A then B) before any compute; B's ride in
    // flight under A's entire pipeline via counted vmcnt.
#pragma unroll
    for (int i = 0; i < 16; ++i) reA[i] = xrA[t + 16 * i];
#pragma unroll
    for (int i = 0; i < 16; ++i) imA[i] = xiA[t + 16 * i];
#pragma unroll
    for (int i = 0; i < 16; ++i) reB[i] = xrB[t + 16 * i];
#pragma unroll
    for (int i = 0; i < 16; ++i) imB[i] = xiB[t + 16 * i];

    float* L = tile + sub * TS;  // wave-private 16x17 tile, reused A then B

    // ---- Batch A
    fft16(reA, imA);
    finish_batch(reA, imA, L, t, out + b0 * 512, out + b0 * 512 + 256);

    // ---- Batch B (loads long since landed)
    fft16(reB, imB);
    finish_batch(reB, imB, L, t, out + b1 * 512, out + b1 * 512 + 256);
}

extern "C" void kernel_launch(void* const* d_in, const int* in_sizes, int n_in,
                              void* d_out, int out_size, void* d_ws, size_t ws_size,
                              hipStream_t stream) {
    (void)d_ws; (void)ws_size; (void)n_in; (void)out_size;
    const float* x = (const float*)d_in[0];
    float* out = (float*)d_out;
    const int batches = in_sizes[0] / 512;        // 131072
    const int grid = batches / (2 * NB);          // 4096 blocks
    fft256_kernel<<<grid, 256, 0, stream>>>(x, out);
}

// Round 11
// 95.747 us; speedup vs baseline: 1.2303x; 1.2178x over previous
//
#include <hip/hip_runtime.h>
#include <math.h>

// 256-point FFT = 16x16 four-step Cooley-Tukey, one batch per 16 lanes,
// TWO batches per thread, software-pipelined: B's 32 loads issue before
// A's compute and ride in flight (counted vmcnt) under A's whole
// FFT+twiddle+store pipeline.
//
// Rounds 9/10 lesson: the AMDGPU backend derives its occupancy TARGET
// from LDS/block. At 17.4 KB (8 blocks/CU possible) it targets 8
// waves/EU -> 64-VGPR budget -> spills the 2-batch state no matter what
// launch_bounds says. Fix: 34.8 KB LDS/block (A and B get separate
// tiles) -> 4 blocks/CU -> target 4 waves/EU -> 128-VGPR budget, no
// spill. Measured occupancy was ~44% anyway, so no real occupancy loss.
//
// Cache policy (round 8): PLAIN loads (input ~50% L3-resident across
// replays, FETCH 230->131MB) + NT stores (write-once output).
// No __syncthreads (wave-private LDS, in-order per-wave DS ops).

#define NB 16   // batch-pairs per 256-thread block (32 batches/block)
#define TS 272  // 16*17 floats per-batch tile

__device__ __forceinline__ void wave_fence() {
    __builtin_amdgcn_wave_barrier();
}

__device__ __forceinline__ void fft16(float re[16], float im[16]) {
    // 4-bit bit-reversal permutation (swap i < rev(i))
    {
        float tr, ti;
#define SWP(a, b) tr = re[a]; re[a] = re[b]; re[b] = tr; ti = im[a]; im[a] = im[b]; im[b] = ti;
        SWP(1, 8) SWP(2, 4) SWP(3, 12) SWP(5, 10) SWP(7, 14) SWP(11, 13)
#undef SWP
    }
    const float C[8] = { 1.0f,  0.92387953251f,  0.70710678119f,  0.38268343236f,
                         0.0f, -0.38268343236f, -0.70710678119f, -0.92387953251f };
    const float S16[8] = { 0.0f, -0.38268343236f, -0.70710678119f, -0.92387953251f,
                          -1.0f, -0.92387953251f, -0.70710678119f, -0.38268343236f };
#pragma unroll
    for (int s = 1; s <= 4; ++s) {
        const int len = 1 << s;
        const int half = len >> 1;
        const int step = 16 >> s;
#pragma unroll
        for (int i = 0; i < 16; i += len) {
#pragma unroll
            for (int j = 0; j < half; ++j) {
                const float wr = C[j * step];
                const float wi = S16[j * step];
                const int p = i + j;
                const int q = i + j + half;
                const float vr = re[q] * wr - im[q] * wi;
                const float vi = re[q] * wi + im[q] * wr;
                const float ur = re[p], ui = im[p];
                re[p] = ur + vr; im[p] = ui + vi;
                re[q] = ur - vr; im[q] = ui - vi;
            }
        }
    }
}

// Twiddle + LDS transpose + second FFT + nt store for one batch.
__device__ __forceinline__ void finish_batch(float re[16], float im[16],
                                             float* L, int t,
                                             float* outr, float* outi) {
#pragma unroll
    for (int k = 0; k < 16; ++k) {
        float sv, cv;
        __sincosf(-6.283185307179586f * (float)(t * k) * (1.0f / 256.0f), &sv, &cv);
        const float tr = re[k] * cv - im[k] * sv;
        const float ti = re[k] * sv + im[k] * cv;
        L[17 * t + k] = ti;   // imag rows to LDS; real kept in re[]
        re[k] = tr;
    }
    wave_fence();
#pragma unroll
    for (int n = 0; n < 16; ++n) im[n] = L[17 * n + t];   // imag columns out
    wave_fence();
#pragma unroll
    for (int k = 0; k < 16; ++k) L[17 * t + k] = re[k];   // real rows in
    wave_fence();
#pragma unroll
    for (int n = 0; n < 16; ++n) re[n] = L[17 * n + t];   // real columns out
    wave_fence();

    fft16(re, im);  // X[t + 16*k1] over k1

#pragma unroll
    for (int k = 0; k < 16; ++k) __builtin_nontemporal_store(re[k], outr + t + 16 * k);
#pragma unroll
    for (int k = 0; k < 16; ++k) __builtin_nontemporal_store(im[k], outi + t + 16 * k);
}

__global__ __launch_bounds__(256, 4) void fft256_kernel(const float* __restrict__ x,
                                                        float* __restrict__ out) {
    // 2*NB tiles: batch A and batch B each get their own. 34816 B/block
    // -> 4 blocks/CU -> backend occupancy target 4 waves/EU -> 128-VGPR
    // budget (the actual point of this sizing; see header comment).
    __shared__ float tile[2 * NB * TS];

    const int tid = threadIdx.x;
    const int sub = tid >> 4;
    const int t   = tid & 15;
    const long b0 = (long)blockIdx.x * (2 * NB) + sub;  // batch A
    const long b1 = b0 + NB;                            // batch B

    const float* xrA = x + b0 * 512;
    const float* xiA = xrA + 256;
    const float* xrB = x + b1 * 512;
    const float* xiB = xrB + 256;

    float reA[16], imA[16], reB[16], imB[16];

    // Issue ALL 64 loads (A then B) before any compute; B's ride in
    // flight under A's entire pipeline via counted vmcnt.
#pragma unroll
    for (int i = 0; i < 16; ++i) reA[i] = xrA[t + 16 * i];
#pragma unroll
    for (int i = 0; i < 16; ++i) imA[i] = xiA[t + 16 * i];
#pragma unroll
    for (int i = 0; i < 16; ++i) reB[i] = xrB[t + 16 * i];
#pragma unroll
    for (int i = 0; i < 16; ++i) imB[i] = xiB[t + 16 * i];

    float* LA = tile + sub * TS;             // batch A tile
    float* LB = tile + (NB + sub) * TS;      // batch B tile

    // ---- Batch A
    fft16(reA, imA);
    finish_batch(reA, imA, LA, t, out + b0 * 512, out + b0 * 512 + 256);

    // ---- Batch B (loads long since landed)
    fft16(reB, imB);
    finish_batch(reB, imB, LB, t, out + b1 * 512, out + b1 * 512 + 256);
}

extern "C" void kernel_launch(void* const* d_in, const int* in_sizes, int n_in,
                              void* d_out, int out_size, void* d_ws, size_t ws_size,
                              hipStream_t stream) {
    (void)d_ws; (void)ws_size; (void)n_in; (void)out_size;
    const float* x = (const float*)d_in[0];
    float* out = (float*)d_out;
    const int batches = in_sizes[0] / 512;        // 131072
    const int grid = batches / (2 * NB);          // 4096 blocks
    fft256_kernel<<<grid, 256, 0, stream>>>(x, out);
}